// Round 14
// baseline (641.473 us; speedup 1.0000x reference)
//
#include <hip/hip_runtime.h>
#include <hip/hip_bf16.h>

typedef __hip_bfloat16 bf16;
typedef __attribute__((ext_vector_type(8))) __bf16 bf16x8;
typedef __attribute__((ext_vector_type(4))) float f32x4;

#define NB 32
#define NQ 300
#define NK 2048
#define NH 8

#define MFMA(a, b, c) __builtin_amdgcn_mfma_f32_16x16x32_bf16(a, b, c, 0, 0, 0)

__device__ __forceinline__ bf16x8 cvt8(float4 a, float4 b) {
    bf16x8 r;
    r[0] = (__bf16)a.x; r[1] = (__bf16)a.y; r[2] = (__bf16)a.z; r[3] = (__bf16)a.w;
    r[4] = (__bf16)b.x; r[5] = (__bf16)b.y; r[6] = (__bf16)b.z; r[7] = (__bf16)b.w;
    return r;
}
__device__ __forceinline__ bf16x8 loadA_f32(const float* p) {
    return cvt8(*(const float4*)p, *(const float4*)(p + 4));
}
__device__ __forceinline__ unsigned pkbf(float a, float b) {
    union { __bf16 h; unsigned short u; } ua, ub;
    ua.h = (__bf16)a; ub.h = (__bf16)b;
    return (unsigned)ua.u | ((unsigned)ub.u << 16);
}

// ---------------------------------------------------------------------------
// wprep: 7 weight matrices [256][256] fp32 -> bf16. order: qc qp kc kp v qs o
// ---------------------------------------------------------------------------
__global__ __launch_bounds__(256) void wprep_kernel(
    const float* __restrict__ w0, const float* __restrict__ w1,
    const float* __restrict__ w2, const float* __restrict__ w3,
    const float* __restrict__ w4, const float* __restrict__ w5,
    const float* __restrict__ w6, bf16* __restrict__ wbf)
{
    const float* Ws[7] = {w0, w1, w2, w3, w4, w5, w6};
    size_t e = ((size_t)blockIdx.x * 256 + threadIdx.x) * 8;
    const float* src = Ws[e >> 16] + (e & 65535);
    bf16x8 v = loadA_f32(src);
    *(bf16x8*)(wbf + e) = v;
}

// ---------------------------------------------------------------------------
// qproj (merged): q_full[..+d]    = 0.125*(hidden@qc^T+qc_b + qpos@qp^T+qp_b)
//                 q_full[..+32+d] = 0.125*(sine@qs^T+qs_b)
// ---------------------------------------------------------------------------
__global__ __launch_bounds__(128) void qproj_kernel(
    const float* __restrict__ XH, const float* __restrict__ XP,
    const float* __restrict__ XS,
    const bf16* __restrict__ WC, const bf16* __restrict__ WP,
    const bf16* __restrict__ WS,
    const float* __restrict__ bc, const float* __restrict__ bp,
    const float* __restrict__ bs, bf16* __restrict__ q_full)
{
    const int t = threadIdx.x, w = t >> 6, l = t & 63, g = l >> 4, c16 = l & 15;
    const int rbase = blockIdx.x * 32 + w * 16;
    const int row = rbase + c16;

    bf16x8 ah[8], ap[8], as_[8];
    #pragma unroll
    for (int ks = 0; ks < 8; ++ks) {
        ah[ks]  = loadA_f32(XH + (size_t)row * 256 + ks * 32 + g * 8);
        ap[ks]  = loadA_f32(XP + (size_t)row * 256 + ks * 32 + g * 8);
        as_[ks] = loadA_f32(XS + (size_t)row * 256 + ks * 32 + g * 8);
    }
    for (int nt = 0; nt < 16; ++nt) {
        const int n = nt * 16 + c16;
        f32x4 accc = {0.f, 0.f, 0.f, 0.f}, accs = {0.f, 0.f, 0.f, 0.f};
        #pragma unroll
        for (int ks = 0; ks < 8; ++ks) {
            bf16x8 bwc = *(const bf16x8*)(WC + (size_t)n * 256 + ks * 32 + g * 8);
            bf16x8 bwp = *(const bf16x8*)(WP + (size_t)n * 256 + ks * 32 + g * 8);
            bf16x8 bws = *(const bf16x8*)(WS + (size_t)n * 256 + ks * 32 + g * 8);
            accc = MFMA(ah[ks], bwc, accc);
            accc = MFMA(ap[ks], bwp, accc);
            accs = MFMA(as_[ks], bws, accs);
        }
        const float bic = bc[n] + bp[n], bis = bs[n];
        const int h = n >> 5, d = n & 31;
        #pragma unroll
        for (int i = 0; i < 4; ++i) {
            const int r = rbase + 4 * g + i;
            const int b_ = (int)(((unsigned)r * 55925u) >> 24);   // r/300
            const int q = r - b_ * 300;
            const size_t base = (((size_t)b_ * 8 + h) * NQ + q) * 64;
            q_full[base + d]      = __float2bfloat16((accc[i] + bic) * 0.125f);
            q_full[base + 32 + d] = __float2bfloat16((accs[i] + bis) * 0.125f);
        }
    }
}

// ---------------------------------------------------------------------------
// kvproj v2: 4x1 wave split — wave w owns 16 rows x all 256 n.
// A-frags 128->64 VGPR => ~2x occupancy vs 2x2 layout (the R14 experiment).
// k_full[..+d] = enc@kc^T+kc_b + (encpos@kp^T+kp_b); [..+32+d] = kp part;
// v_t[bh][d][k] = enc@v^T+v_b.
// ---------------------------------------------------------------------------
__global__ __launch_bounds__(256) void kvproj_kernel(
    const float* __restrict__ X1, const float* __restrict__ X2,
    const bf16* __restrict__ W1, const bf16* __restrict__ W2,
    const bf16* __restrict__ WV,
    const float* __restrict__ b1, const float* __restrict__ b2,
    const float* __restrict__ bvb,
    bf16* __restrict__ k_full, bf16* __restrict__ v_t)
{
    const int t = threadIdx.x, w = t >> 6, l = t & 63, g = l >> 4, c16 = l & 15;
    const int r0 = blockIdx.x * 64 + w * 16;
    const int row = r0 + c16;

    bf16x8 a1[8], a2[8];
    #pragma unroll
    for (int ks = 0; ks < 8; ++ks) {
        a1[ks] = loadA_f32(X1 + (size_t)row * 256 + ks * 32 + g * 8);
        a2[ks] = loadA_f32(X2 + (size_t)row * 256 + ks * 32 + g * 8);
    }
    const int b_ = r0 >> 11;           // 16-row run never crosses a 2048 boundary
    const int kk = (r0 & 2047) + 4 * g;

    for (int nt = 0; nt < 16; ++nt) {
        const int n = nt * 16 + c16;
        f32x4 ac = {0.f,0.f,0.f,0.f}, ap = {0.f,0.f,0.f,0.f}, av = {0.f,0.f,0.f,0.f};
        #pragma unroll
        for (int ks = 0; ks < 8; ++ks) {
            bf16x8 bw1 = *(const bf16x8*)(W1 + (size_t)n * 256 + ks * 32 + g * 8);
            bf16x8 bw2 = *(const bf16x8*)(W2 + (size_t)n * 256 + ks * 32 + g * 8);
            bf16x8 bwv = *(const bf16x8*)(WV + (size_t)n * 256 + ks * 32 + g * 8);
            ac = MFMA(a1[ks], bw1, ac);
            ap = MFMA(a2[ks], bw2, ap);
            av = MFMA(a1[ks], bwv, av);
        }
        const float bcn = b1[n], bpn = b2[n], bvn = bvb[n];
        const int h = n >> 5, d = n & 31;
        #pragma unroll
        for (int i = 0; i < 4; ++i) {
            const size_t base = ((size_t)(b_ * 8 + h) * NK + kk + i) * 64;
            const float yp = ap[i] + bpn;
            k_full[base + d]      = __float2bfloat16(ac[i] + bcn + yp);
            k_full[base + 32 + d] = __float2bfloat16(yp);
        }
        uint2 vpk = { pkbf(av[0] + bvn, av[1] + bvn),
                      pkbf(av[2] + bvn, av[3] + bvn) };
        *(uint2*)&v_t[((size_t)(b_ * 8 + h) * 32 + d) * NK + kk] = vpk;
    }
}

// ---------------------------------------------------------------------------
// attn1: cooperative denominator pass. Block = (bh, 64 q); wave w covers
// k in [512w, 512w+512) for all 64 q. Writes inv[bh][q] = 1/sum.
// ---------------------------------------------------------------------------
__global__ __launch_bounds__(256) void attn1_kernel(
    const bf16* __restrict__ q_full, const bf16* __restrict__ k_full,
    float* __restrict__ inv_arr)
{
    __shared__ float psum[4][64];

    const int t = threadIdx.x, w = t >> 6, l = t & 63;
    const int g = l >> 4, c16 = l & 15;

    const int p = blockIdx.x;
    const int lid = (p & 7) * 160 + (p >> 3);
    const int bh = (int)(((unsigned)lid * 6554u) >> 15);   // lid/5 (lid<1280)
    const int blk = lid - bh * 5;

    const size_t qbase = (size_t)bh * NQ * 64;
    const size_t kbase = (size_t)bh * NK * 64;

    bf16x8 qt0[4], qt1[4];
    #pragma unroll
    for (int qt = 0; qt < 4; ++qt) {
        const int qr = min(blk * 64 + qt * 16 + c16, NQ - 1);
        qt0[qt] = *(const bf16x8*)(q_full + qbase + (size_t)qr * 64 + g * 8);
        qt1[qt] = *(const bf16x8*)(q_full + qbase + (size_t)qr * 64 + 32 + g * 8);
    }
    float sums[4] = {0.f, 0.f, 0.f, 0.f};
    const int kw0 = w * 512;
    for (int ch = 0; ch < 32; ++ch) {
        const bf16* kap = k_full + kbase + (size_t)(kw0 + ch * 16 + c16) * 64 + g * 8;
        bf16x8 ka0 = *(const bf16x8*)(kap);
        bf16x8 ka1 = *(const bf16x8*)(kap + 32);
        #pragma unroll
        for (int qt = 0; qt < 4; ++qt) {
            f32x4 sa = {0.f, 0.f, 0.f, 0.f};
            sa = MFMA(ka0, qt0[qt], sa);
            sa = MFMA(ka1, qt1[qt], sa);
            sums[qt] += __expf(sa[0]) + __expf(sa[1])
                      + __expf(sa[2]) + __expf(sa[3]);
        }
    }
    #pragma unroll
    for (int qt = 0; qt < 4; ++qt) {
        sums[qt] += __shfl_xor(sums[qt], 16);
        sums[qt] += __shfl_xor(sums[qt], 32);
    }
    if (l < 16) {
        #pragma unroll
        for (int qt = 0; qt < 4; ++qt) psum[w][qt * 16 + l] = sums[qt];
    }
    __syncthreads();

    if (t < 64) {
        const int q = blk * 64 + t;
        if (q < NQ)
            inv_arr[(size_t)bh * NQ + q] =
                1.f / (psum[0][t] + psum[1][t] + psum[2][t] + psum[3][t]);
    }
}

// ---------------------------------------------------------------------------
// attn2: prob + PV pass — REVERTED to the R10 store path (nontemporal 64B
// direct-from-register), which passed post-timing validation twice.
// {nt,64B}=253us is the best of the 2x2 store matrix; the pstore LDS-remap
// variants are retired after R13's determinism trip.
// Block = (bh, 64 q); wave = 16 q, full k, 2-deep register prefetch.
// ---------------------------------------------------------------------------
__global__ __launch_bounds__(256) void attn2_kernel(
    const bf16* __restrict__ q_full, const bf16* __restrict__ k_full,
    const bf16* __restrict__ v_t, const float* __restrict__ inv_arr,
    float* __restrict__ w_out, float* __restrict__ attn_tmp)
{
    __shared__ __align__(16) unsigned paw[4][256];

    const int t = threadIdx.x, w = t >> 6, l = t & 63;
    const int g = l >> 4, c16 = l & 15;
    const int s4 = (c16 & 3) << 2;          // LDS xor swizzle (4-u32 units)

    const int p = blockIdx.x;
    const int lid = (p & 7) * 160 + (p >> 3);
    const int bh = (int)(((unsigned)lid * 6554u) >> 15);   // lid/5 (lid<1280)
    const int blk = lid - bh * 5;
    const int q0 = blk * 64 + w * 16;
    if (q0 >= NQ) return;   // idle tail wave (blk 4, wave 3)

    const size_t qbase = (size_t)bh * NQ * 64;
    const size_t kbase = (size_t)bh * NK * 64;
    const size_t vbase = (size_t)bh * 32 * NK;

    const int qrm = min(q0 + c16, NQ - 1);
    bf16x8 qf0 = *(const bf16x8*)(q_full + qbase + (size_t)qrm * 64 + g * 8);
    bf16x8 qf1 = *(const bf16x8*)(q_full + qbase + (size_t)qrm * 64 + 32 + g * 8);
    const float inv = inv_arr[(size_t)bh * NQ + qrm];

    const bool qok = (q0 + c16) < NQ;
    float* wrow = w_out + ((size_t)bh * NQ + q0 + c16) * NK;
    unsigned* pawW = paw[w];
    const bf16* kbp = k_full + kbase;
    const bf16* vbp = v_t + vbase;
    f32x4 oa0 = {0.f, 0.f, 0.f, 0.f}, oa1 = {0.f, 0.f, 0.f, 0.f};

#define LDK(c, K00, K01, K10, K11) do { \
    const bf16* _kap = kbp + (size_t)((c) * 32 + c16) * 64 + g * 8; \
    K00 = *(const bf16x8*)(_kap); \
    K01 = *(const bf16x8*)(_kap + 32); \
    K10 = *(const bf16x8*)(_kap + 16 * 64); \
    K11 = *(const bf16x8*)(_kap + 16 * 64 + 32); \
} while (0)
#define LDV(c, V0, V1) do { \
    const bf16* _vp = vbp + (size_t)c16 * NK + (c) * 32 + g * 8; \
    V0 = *(const bf16x8*)(_vp); \
    V1 = *(const bf16x8*)(_vp + 16 * NK); \
} while (0)

#define BODY(c, K00, K01, K10, K11, V0, V1) do { \
    const int _k0 = (c) * 32; \
    const int _cn = ((c) + 2 < 64) ? (c) + 2 : 62; \
    f32x4 _slo = {0.f,0.f,0.f,0.f}, _shi = {0.f,0.f,0.f,0.f}; \
    _slo = MFMA(K00, qf0, _slo); _slo = MFMA(K01, qf1, _slo); \
    _shi = MFMA(K10, qf0, _shi); _shi = MFMA(K11, qf1, _shi); \
    LDK(_cn, K00, K01, K10, K11);   /* refill K (already consumed) */ \
    float _plo[4], _phi[4]; \
    _Pragma("unroll") \
    for (int _i = 0; _i < 4; ++_i) { \
        _plo[_i] = __expf(_slo[_i]) * inv; \
        _phi[_i] = __expf(_shi[_i]) * inv; \
    } \
    uint2 _lo2 = { pkbf(_plo[0], _plo[1]), pkbf(_plo[2], _plo[3]) }; \
    uint2 _hi2 = { pkbf(_phi[0], _phi[1]), pkbf(_phi[2], _phi[3]) }; \
    *(uint2*)&pawW[c16 * 16 + ((2 * g) ^ s4)]     = _lo2; \
    *(uint2*)&pawW[c16 * 16 + ((8 + 2 * g) ^ s4)] = _hi2; \
    union { uint4 q; bf16x8 v; } _A; \
    _A.q = *(uint4*)&pawW[c16 * 16 + ((4 * g) ^ s4)]; \
    oa0 = MFMA(_A.v, V0, oa0); \
    oa1 = MFMA(_A.v, V1, oa1); \
    LDV(_cn, V0, V1);               /* refill V (already consumed) */ \
    if (qok) {                       /* stores last: never poison load waits */ \
        f32x4 _vlo = {_plo[0], _plo[1], _plo[2], _plo[3]}; \
        f32x4 _vhi = {_phi[0], _phi[1], _phi[2], _phi[3]}; \
        __builtin_nontemporal_store(_vlo, (f32x4*)(wrow + _k0 + 4 * g)); \
        __builtin_nontemporal_store(_vhi, (f32x4*)(wrow + _k0 + 16 + 4 * g)); \
    } \
} while (0)

    bf16x8 Ak00, Ak01, Ak10, Ak11, Av0, Av1;
    bf16x8 Bk00, Bk01, Bk10, Bk11, Bv0, Bv1;
    LDK(0, Ak00, Ak01, Ak10, Ak11);  LDV(0, Av0, Av1);
    LDK(1, Bk00, Bk01, Bk10, Bk11);  LDV(1, Bv0, Bv1);

    for (int c = 0; c < 64; c += 2) {
        BODY(c,     Ak00, Ak01, Ak10, Ak11, Av0, Av1);
        BODY(c + 1, Bk00, Bk01, Bk10, Bk11, Bv0, Bv1);
    }

    // O store: D col=c16=d, row q=4g+i
    const int b_ = bh >> 3, h = bh & 7;
    #pragma unroll
    for (int i = 0; i < 4; ++i) {
        const int q = q0 + 4 * g + i;
        if (q < NQ) {
            float* orow = attn_tmp + ((size_t)b_ * NQ + q) * 256 + h * 32;
            orow[c16]      = oa0[i];
            orow[16 + c16] = oa1[i];
        }
    }
}

// ---------------------------------------------------------------------------
// oproj: out = attn_tmp @ o^T + o_b (fp32 out). 150 blocks.
// ---------------------------------------------------------------------------
__global__ __launch_bounds__(256) void oproj_kernel(
    const float* __restrict__ X1, const bf16* __restrict__ W1,
    const float* __restrict__ b1, float* __restrict__ out)
{
    const int t = threadIdx.x, w = t >> 6, l = t & 63, g = l >> 4, c16 = l & 15;
    const int wm = w >> 1, wn = w & 1;
    const int r0 = blockIdx.x * 64 + wm * 32;

    bf16x8 a1[2][8];
    #pragma unroll
    for (int mt = 0; mt < 2; ++mt) {
        const int row = r0 + mt * 16 + c16;
        #pragma unroll
        for (int ks = 0; ks < 8; ++ks)
            a1[mt][ks] = loadA_f32(X1 + (size_t)row * 256 + ks * 32 + g * 8);
    }
    #pragma unroll
    for (int nt = 0; nt < 8; ++nt) {
        const int n = wn * 128 + nt * 16 + c16;
        f32x4 acc0 = {0.f,0.f,0.f,0.f}, acc1 = {0.f,0.f,0.f,0.f};
        #pragma unroll
        for (int ks = 0; ks < 8; ++ks) {
            bf16x8 bw1 = *(const bf16x8*)(W1 + (size_t)n * 256 + ks * 32 + g * 8);
            acc0 = MFMA(a1[0][ks], bw1, acc0);
            acc1 = MFMA(a1[1][ks], bw1, acc1);
        }
        const float bias = b1[n];
        #pragma unroll
        for (int mt = 0; mt < 2; ++mt) {
            f32x4 acc = mt ? acc1 : acc0;
            #pragma unroll
            for (int i = 0; i < 4; ++i) {
                const int r = r0 + mt * 16 + 4 * g + i;
                out[(size_t)r * 256 + n] = acc[i] + bias;
            }
        }
    }
}

// ---------------------------------------------------------------------------
extern "C" void kernel_launch(void* const* d_in, const int* in_sizes, int n_in,
                              void* d_out, int out_size, void* d_ws, size_t ws_size,
                              hipStream_t stream) {
    const float* hidden = (const float*)d_in[0];
    const float* enc    = (const float*)d_in[1];
    const float* sine   = (const float*)d_in[2];
    const float* encpos = (const float*)d_in[3];
    const float* qpos   = (const float*)d_in[4];
    const float* qc_w = (const float*)d_in[5];  const float* qc_b = (const float*)d_in[6];
    const float* qp_w = (const float*)d_in[7];  const float* qp_b = (const float*)d_in[8];
    const float* kc_w = (const float*)d_in[9];  const float* kc_b = (const float*)d_in[10];
    const float* kp_w = (const float*)d_in[11]; const float* kp_b = (const float*)d_in[12];
    const float* v_w  = (const float*)d_in[13]; const float* v_b  = (const float*)d_in[14];
    const float* qs_w = (const float*)d_in[15]; const float* qs_b = (const float*)d_in[16];
    const float* o_w  = (const float*)d_in[17]; const float* o_b  = (const float*)d_in[18];

    float* out = (float*)d_out;
    float* attn_out = out;                          // [B][Q][256]
    float* w_out    = out + (size_t)NB * NQ * 256;  // [B][NH][Q][K]

    char* ws = (char*)d_ws;
    bf16* q_full    = (bf16*)ws;                        //  9,830,400
    bf16* k_full    = (bf16*)(ws + 9830400);            // 67,108,864
    bf16* v_t       = (bf16*)(ws + 76939264);           // 33,554,432
    float* attn_tmp = (float*)(ws + 110493696);         //  9,830,400
    bf16* wbf       = (bf16*)(ws + 120324096);          //    917,504
    float* inv_arr  = (float*)(ws + 121241600);         //    307,200

    wprep_kernel<<<224, 256, 0, stream>>>(qc_w, qp_w, kc_w, kp_w, v_w, qs_w, o_w, wbf);

    qproj_kernel<<<300, 128, 0, stream>>>(hidden, qpos, sine,
        wbf + 0 * 65536, wbf + 1 * 65536, wbf + 5 * 65536,
        qc_b, qp_b, qs_b, q_full);
    kvproj_kernel<<<1024, 256, 0, stream>>>(enc, encpos,
        wbf + 2 * 65536, wbf + 3 * 65536, wbf + 4 * 65536,
        kc_b, kp_b, v_b, k_full, v_t);

    attn1_kernel<<<1280, 256, 0, stream>>>(q_full, k_full, inv_arr);
    attn2_kernel<<<1280, 256, 0, stream>>>(q_full, k_full, v_t, inv_arr, w_out, attn_tmp);

    oproj_kernel<<<150, 256, 0, stream>>>(attn_tmp, wbf + 6 * 65536, o_b, attn_out);
}

// Round 15
// 519.226 us; speedup vs baseline: 1.2354x; 1.2354x over previous
//
#include <hip/hip_runtime.h>
#include <hip/hip_bf16.h>

typedef __hip_bfloat16 bf16;
typedef __attribute__((ext_vector_type(8))) __bf16 bf16x8;
typedef __attribute__((ext_vector_type(4))) float f32x4;

#define NB 32
#define NQ 300
#define NK 2048
#define NH 8

#define MFMA(a, b, c) __builtin_amdgcn_mfma_f32_16x16x32_bf16(a, b, c, 0, 0, 0)

__device__ __forceinline__ bf16x8 cvt8(float4 a, float4 b) {
    bf16x8 r;
    r[0] = (__bf16)a.x; r[1] = (__bf16)a.y; r[2] = (__bf16)a.z; r[3] = (__bf16)a.w;
    r[4] = (__bf16)b.x; r[5] = (__bf16)b.y; r[6] = (__bf16)b.z; r[7] = (__bf16)b.w;
    return r;
}
__device__ __forceinline__ bf16x8 loadA_f32(const float* p) {
    return cvt8(*(const float4*)p, *(const float4*)(p + 4));
}
__device__ __forceinline__ unsigned pkbf(float a, float b) {
    union { __bf16 h; unsigned short u; } ua, ub;
    ua.h = (__bf16)a; ub.h = (__bf16)b;
    return (unsigned)ua.u | ((unsigned)ub.u << 16);
}

// ---------------------------------------------------------------------------
// wprep: 7 weight matrices [256][256] fp32 -> bf16. order: qc qp kc kp v qs o
// ---------------------------------------------------------------------------
__global__ __launch_bounds__(256) void wprep_kernel(
    const float* __restrict__ w0, const float* __restrict__ w1,
    const float* __restrict__ w2, const float* __restrict__ w3,
    const float* __restrict__ w4, const float* __restrict__ w5,
    const float* __restrict__ w6, bf16* __restrict__ wbf)
{
    const float* Ws[7] = {w0, w1, w2, w3, w4, w5, w6};
    size_t e = ((size_t)blockIdx.x * 256 + threadIdx.x) * 8;
    const float* src = Ws[e >> 16] + (e & 65535);
    bf16x8 v = loadA_f32(src);
    *(bf16x8*)(wbf + e) = v;
}

// ---------------------------------------------------------------------------
// qproj (merged): q_full[..+d]    = 0.125*(hidden@qc^T+qc_b + qpos@qp^T+qp_b)
//                 q_full[..+32+d] = 0.125*(sine@qs^T+qs_b)
// ---------------------------------------------------------------------------
__global__ __launch_bounds__(128) void qproj_kernel(
    const float* __restrict__ XH, const float* __restrict__ XP,
    const float* __restrict__ XS,
    const bf16* __restrict__ WC, const bf16* __restrict__ WP,
    const bf16* __restrict__ WS,
    const float* __restrict__ bc, const float* __restrict__ bp,
    const float* __restrict__ bs, bf16* __restrict__ q_full)
{
    const int t = threadIdx.x, w = t >> 6, l = t & 63, g = l >> 4, c16 = l & 15;
    const int rbase = blockIdx.x * 32 + w * 16;
    const int row = rbase + c16;

    bf16x8 ah[8], ap[8], as_[8];
    #pragma unroll
    for (int ks = 0; ks < 8; ++ks) {
        ah[ks]  = loadA_f32(XH + (size_t)row * 256 + ks * 32 + g * 8);
        ap[ks]  = loadA_f32(XP + (size_t)row * 256 + ks * 32 + g * 8);
        as_[ks] = loadA_f32(XS + (size_t)row * 256 + ks * 32 + g * 8);
    }
    for (int nt = 0; nt < 16; ++nt) {
        const int n = nt * 16 + c16;
        f32x4 accc = {0.f, 0.f, 0.f, 0.f}, accs = {0.f, 0.f, 0.f, 0.f};
        #pragma unroll
        for (int ks = 0; ks < 8; ++ks) {
            bf16x8 bwc = *(const bf16x8*)(WC + (size_t)n * 256 + ks * 32 + g * 8);
            bf16x8 bwp = *(const bf16x8*)(WP + (size_t)n * 256 + ks * 32 + g * 8);
            bf16x8 bws = *(const bf16x8*)(WS + (size_t)n * 256 + ks * 32 + g * 8);
            accc = MFMA(ah[ks], bwc, accc);
            accc = MFMA(ap[ks], bwp, accc);
            accs = MFMA(as_[ks], bws, accs);
        }
        const float bic = bc[n] + bp[n], bis = bs[n];
        const int h = n >> 5, d = n & 31;
        #pragma unroll
        for (int i = 0; i < 4; ++i) {
            const int r = rbase + 4 * g + i;
            const int b_ = (int)(((unsigned)r * 55925u) >> 24);   // r/300
            const int q = r - b_ * 300;
            const size_t base = (((size_t)b_ * 8 + h) * NQ + q) * 64;
            q_full[base + d]      = __float2bfloat16((accc[i] + bic) * 0.125f);
            q_full[base + 32 + d] = __float2bfloat16((accs[i] + bis) * 0.125f);
        }
    }
}

// ---------------------------------------------------------------------------
// kvproj (REVERTED to the 2x2-wave layout — R14's 4x1 split cost ~120us by
// doubling per-wave weight reads): k_full[..+d] = enc@kc^T+kc_b +
// (encpos@kp^T+kp_b); [..+32+d] = kp part; v_t[bh][d][k] = enc@v^T+v_b.
// ---------------------------------------------------------------------------
__global__ __launch_bounds__(256) void kvproj_kernel(
    const float* __restrict__ X1, const float* __restrict__ X2,
    const bf16* __restrict__ W1, const bf16* __restrict__ W2,
    const bf16* __restrict__ WV,
    const float* __restrict__ b1, const float* __restrict__ b2,
    const float* __restrict__ bvb,
    bf16* __restrict__ k_full, bf16* __restrict__ v_t)
{
    const int t = threadIdx.x, w = t >> 6, l = t & 63, g = l >> 4, c16 = l & 15;
    const int wm = w >> 1, wn = w & 1;
    const int r0 = blockIdx.x * 64 + wm * 32;

    bf16x8 a1[2][8], a2[2][8];
    #pragma unroll
    for (int mt = 0; mt < 2; ++mt) {
        const int row = r0 + mt * 16 + c16;
        #pragma unroll
        for (int ks = 0; ks < 8; ++ks) {
            a1[mt][ks] = loadA_f32(X1 + (size_t)row * 256 + ks * 32 + g * 8);
            a2[mt][ks] = loadA_f32(X2 + (size_t)row * 256 + ks * 32 + g * 8);
        }
    }
    #pragma unroll
    for (int nt = 0; nt < 8; ++nt) {
        const int n = wn * 128 + nt * 16 + c16;
        f32x4 ac0 = {0.f,0.f,0.f,0.f}, ac1 = {0.f,0.f,0.f,0.f};
        f32x4 ap0 = {0.f,0.f,0.f,0.f}, ap1 = {0.f,0.f,0.f,0.f};
        f32x4 av0 = {0.f,0.f,0.f,0.f}, av1 = {0.f,0.f,0.f,0.f};
        #pragma unroll
        for (int ks = 0; ks < 8; ++ks) {
            bf16x8 bw1 = *(const bf16x8*)(W1 + (size_t)n * 256 + ks * 32 + g * 8);
            bf16x8 bw2 = *(const bf16x8*)(W2 + (size_t)n * 256 + ks * 32 + g * 8);
            bf16x8 bwv = *(const bf16x8*)(WV + (size_t)n * 256 + ks * 32 + g * 8);
            ac0 = MFMA(a1[0][ks], bw1, ac0);
            ap0 = MFMA(a2[0][ks], bw2, ap0);
            av0 = MFMA(a1[0][ks], bwv, av0);
            ac1 = MFMA(a1[1][ks], bw1, ac1);
            ap1 = MFMA(a2[1][ks], bw2, ap1);
            av1 = MFMA(a1[1][ks], bwv, av1);
        }
        const float bcn = b1[n], bpn = b2[n], bvn = bvb[n];
        const int h = n >> 5, d = n & 31;
        #pragma unroll
        for (int mt = 0; mt < 2; ++mt) {
            f32x4 accc = mt ? ac1 : ac0;
            f32x4 accp = mt ? ap1 : ap0;
            f32x4 accv = mt ? av1 : av0;
            const int rr = r0 + mt * 16 + 4 * g;      // 4-run start (same b_)
            const int b_ = rr >> 11, kk = rr & 2047;
            #pragma unroll
            for (int i = 0; i < 4; ++i) {
                const size_t base = ((size_t)(b_ * 8 + h) * NK + kk + i) * 64;
                const float yp = accp[i] + bpn;
                k_full[base + d]      = __float2bfloat16(accc[i] + bcn + yp);
                k_full[base + 32 + d] = __float2bfloat16(yp);
            }
            uint2 vpk = { pkbf(accv[0] + bvn, accv[1] + bvn),
                          pkbf(accv[2] + bvn, accv[3] + bvn) };
            *(uint2*)&v_t[((size_t)(b_ * 8 + h) * 32 + d) * NK + kk] = vpk;
        }
    }
}

// ---------------------------------------------------------------------------
// attn1: cooperative denominator pass. Block = (bh, 64 q); wave w covers
// k in [512w, 512w+512) for all 64 q. Writes inv[bh][q] = 1/sum.
// ---------------------------------------------------------------------------
__global__ __launch_bounds__(256) void attn1_kernel(
    const bf16* __restrict__ q_full, const bf16* __restrict__ k_full,
    float* __restrict__ inv_arr)
{
    __shared__ float psum[4][64];

    const int t = threadIdx.x, w = t >> 6, l = t & 63;
    const int g = l >> 4, c16 = l & 15;

    const int p = blockIdx.x;
    const int lid = (p & 7) * 160 + (p >> 3);
    const int bh = (int)(((unsigned)lid * 6554u) >> 15);   // lid/5 (lid<1280)
    const int blk = lid - bh * 5;

    const size_t qbase = (size_t)bh * NQ * 64;
    const size_t kbase = (size_t)bh * NK * 64;

    bf16x8 qt0[4], qt1[4];
    #pragma unroll
    for (int qt = 0; qt < 4; ++qt) {
        const int qr = min(blk * 64 + qt * 16 + c16, NQ - 1);
        qt0[qt] = *(const bf16x8*)(q_full + qbase + (size_t)qr * 64 + g * 8);
        qt1[qt] = *(const bf16x8*)(q_full + qbase + (size_t)qr * 64 + 32 + g * 8);
    }
    float sums[4] = {0.f, 0.f, 0.f, 0.f};
    const int kw0 = w * 512;
    for (int ch = 0; ch < 32; ++ch) {
        const bf16* kap = k_full + kbase + (size_t)(kw0 + ch * 16 + c16) * 64 + g * 8;
        bf16x8 ka0 = *(const bf16x8*)(kap);
        bf16x8 ka1 = *(const bf16x8*)(kap + 32);
        #pragma unroll
        for (int qt = 0; qt < 4; ++qt) {
            f32x4 sa = {0.f, 0.f, 0.f, 0.f};
            sa = MFMA(ka0, qt0[qt], sa);
            sa = MFMA(ka1, qt1[qt], sa);
            sums[qt] += __expf(sa[0]) + __expf(sa[1])
                      + __expf(sa[2]) + __expf(sa[3]);
        }
    }
    #pragma unroll
    for (int qt = 0; qt < 4; ++qt) {
        sums[qt] += __shfl_xor(sums[qt], 16);
        sums[qt] += __shfl_xor(sums[qt], 32);
    }
    if (l < 16) {
        #pragma unroll
        for (int qt = 0; qt < 4; ++qt) psum[w][qt * 16 + l] = sums[qt];
    }
    __syncthreads();

    if (t < 64) {
        const int q = blk * 64 + t;
        if (q < NQ)
            inv_arr[(size_t)bh * NQ + q] =
                1.f / (psum[0][t] + psum[1][t] + psum[2][t] + psum[3][t]);
    }
}

// ---------------------------------------------------------------------------
// attn2: prob + PV pass. Block = (bh, 64 q); wave = 16 q, full k, 2-deep
// register prefetch. Store path: batch 4 chunks of fp32 probs in a
// wave-private LDS tile [16][132] (pad kills write conflicts), then flush
// with 8 nt store instructions, each = 2 rows x 512B CONTIGUOUS bursts.
// Mechanism target: grow per-row burst 128B->512B (stream-pattern fix);
// nt kept (L2-bypass, +95us proven vs plain in R11).
// ---------------------------------------------------------------------------
__global__ __launch_bounds__(256) void attn2_kernel(
    const bf16* __restrict__ q_full, const bf16* __restrict__ k_full,
    const bf16* __restrict__ v_t, const float* __restrict__ inv_arr,
    float* __restrict__ w_out, float* __restrict__ attn_tmp)
{
    __shared__ __align__(16) unsigned paw[4][256];
    __shared__ __align__(16) float pstore[4][16][132];   // 33KB: 4-chunk batches

    const int t = threadIdx.x, w = t >> 6, l = t & 63;
    const int g = l >> 4, c16 = l & 15;
    const int s4 = (c16 & 3) << 2;          // LDS xor swizzle (4-u32 units)

    const int p = blockIdx.x;
    const int lid = (p & 7) * 160 + (p >> 3);
    const int bh = (int)(((unsigned)lid * 6554u) >> 15);   // lid/5 (lid<1280)
    const int blk = lid - bh * 5;
    const int q0 = blk * 64 + w * 16;
    if (q0 >= NQ) return;   // idle tail wave (blk 4, wave 3)

    const size_t qbase = (size_t)bh * NQ * 64;
    const size_t kbase = (size_t)bh * NK * 64;
    const size_t vbase = (size_t)bh * 32 * NK;

    const int qrm = min(q0 + c16, NQ - 1);
    bf16x8 qf0 = *(const bf16x8*)(q_full + qbase + (size_t)qrm * 64 + g * 8);
    bf16x8 qf1 = *(const bf16x8*)(q_full + qbase + (size_t)qrm * 64 + 32 + g * 8);
    const float inv = inv_arr[(size_t)bh * NQ + qrm];

    float* wbase = w_out + ((size_t)bh * NQ + q0) * NK;
    unsigned* pawW = paw[w];
    float* psW = &pstore[w][0][0];
    const bf16* kbp = k_full + kbase;
    const bf16* vbp = v_t + vbase;
    const int l31 = l & 31, lhi = l >> 5;   // flush: row pair + 16B column
    f32x4 oa0 = {0.f, 0.f, 0.f, 0.f}, oa1 = {0.f, 0.f, 0.f, 0.f};

#define LDK(c, K00, K01, K10, K11) do { \
    const bf16* _kap = kbp + (size_t)((c) * 32 + c16) * 64 + g * 8; \
    K00 = *(const bf16x8*)(_kap); \
    K01 = *(const bf16x8*)(_kap + 32); \
    K10 = *(const bf16x8*)(_kap + 16 * 64); \
    K11 = *(const bf16x8*)(_kap + 16 * 64 + 32); \
} while (0)
#define LDV(c, V0, V1) do { \
    const bf16* _vp = vbp + (size_t)c16 * NK + (c) * 32 + g * 8; \
    V0 = *(const bf16x8*)(_vp); \
    V1 = *(const bf16x8*)(_vp + 16 * NK); \
} while (0)

#define BODY(c, cb, K00, K01, K10, K11, V0, V1) do { \
    const int _cn = ((c) + 2 < 64) ? (c) + 2 : 62; \
    f32x4 _slo = {0.f,0.f,0.f,0.f}, _shi = {0.f,0.f,0.f,0.f}; \
    _slo = MFMA(K00, qf0, _slo); _slo = MFMA(K01, qf1, _slo); \
    _shi = MFMA(K10, qf0, _shi); _shi = MFMA(K11, qf1, _shi); \
    LDK(_cn, K00, K01, K10, K11);   /* refill K (already consumed) */ \
    f32x4 _vlo, _vhi; \
    _Pragma("unroll") \
    for (int _i = 0; _i < 4; ++_i) { \
        _vlo[_i] = __expf(_slo[_i]) * inv; \
        _vhi[_i] = __expf(_shi[_i]) * inv; \
    } \
    uint2 _lo2 = { pkbf(_vlo[0], _vlo[1]), pkbf(_vlo[2], _vlo[3]) }; \
    uint2 _hi2 = { pkbf(_vhi[0], _vhi[1]), pkbf(_vhi[2], _vhi[3]) }; \
    *(uint2*)&pawW[c16 * 16 + ((2 * g) ^ s4)]     = _lo2; \
    *(uint2*)&pawW[c16 * 16 + ((8 + 2 * g) ^ s4)] = _hi2; \
    *(f32x4*)(psW + c16 * 132 + (cb) * 32 + 4 * g)      = _vlo; \
    *(f32x4*)(psW + c16 * 132 + (cb) * 32 + 16 + 4 * g) = _vhi; \
    union { uint4 q; bf16x8 v; } _A; \
    _A.q = *(uint4*)&pawW[c16 * 16 + ((4 * g) ^ s4)]; \
    oa0 = MFMA(_A.v, V0, oa0); \
    oa1 = MFMA(_A.v, V1, oa1); \
    LDV(_cn, V0, V1);               /* refill V (already consumed) */ \
} while (0)

    bf16x8 Ak00, Ak01, Ak10, Ak11, Av0, Av1;
    bf16x8 Bk00, Bk01, Bk10, Bk11, Bv0, Bv1;
    LDK(0, Ak00, Ak01, Ak10, Ak11);  LDV(0, Av0, Av1);
    LDK(1, Bk00, Bk01, Bk10, Bk11);  LDV(1, Bv0, Bv1);

    for (int b = 0; b < 16; ++b) {
        const int c0 = b * 4;
        BODY(c0,     0, Ak00, Ak01, Ak10, Ak11, Av0, Av1);
        BODY(c0 + 1, 1, Bk00, Bk01, Bk10, Bk11, Bv0, Bv1);
        BODY(c0 + 2, 2, Ak00, Ak01, Ak10, Ak11, Av0, Av1);
        BODY(c0 + 3, 3, Bk00, Bk01, Bk10, Bk11, Bv0, Bv1);
        // flush: 8 insts, each 2 rows x 512B contiguous (nt, L2-bypass)
        #pragma unroll
        for (int pr = 0; pr < 8; ++pr) {
            const int r = 2 * pr + lhi;
            f32x4 pv = *(const f32x4*)(psW + r * 132 + 4 * l31);
            if (q0 + r < NQ)
                __builtin_nontemporal_store(pv,
                    (f32x4*)(wbase + (size_t)r * NK + c0 * 32 + 4 * l31));
        }
    }

    // O store: D col=c16=d, row q=4g+i
    const int b_ = bh >> 3, h = bh & 7;
    #pragma unroll
    for (int i = 0; i < 4; ++i) {
        const int q = q0 + 4 * g + i;
        if (q < NQ) {
            float* orow = attn_tmp + ((size_t)b_ * NQ + q) * 256 + h * 32;
            orow[c16]      = oa0[i];
            orow[16 + c16] = oa1[i];
        }
    }
}

// ---------------------------------------------------------------------------
// oproj: out = attn_tmp @ o^T + o_b (fp32 out). 150 blocks.
// ---------------------------------------------------------------------------
__global__ __launch_bounds__(256) void oproj_kernel(
    const float* __restrict__ X1, const bf16* __restrict__ W1,
    const float* __restrict__ b1, float* __restrict__ out)
{
    const int t = threadIdx.x, w = t >> 6, l = t & 63, g = l >> 4, c16 = l & 15;
    const int wm = w >> 1, wn = w & 1;
    const int r0 = blockIdx.x * 64 + wm * 32;

    bf16x8 a1[2][8];
    #pragma unroll
    for (int mt = 0; mt < 2; ++mt) {
        const int row = r0 + mt * 16 + c16;
        #pragma unroll
        for (int ks = 0; ks < 8; ++ks)
            a1[mt][ks] = loadA_f32(X1 + (size_t)row * 256 + ks * 32 + g * 8);
    }
    #pragma unroll
    for (int nt = 0; nt < 8; ++nt) {
        const int n = wn * 128 + nt * 16 + c16;
        f32x4 acc0 = {0.f,0.f,0.f,0.f}, acc1 = {0.f,0.f,0.f,0.f};
        #pragma unroll
        for (int ks = 0; ks < 8; ++ks) {
            bf16x8 bw1 = *(const bf16x8*)(W1 + (size_t)n * 256 + ks * 32 + g * 8);
            acc0 = MFMA(a1[0][ks], bw1, acc0);
            acc1 = MFMA(a1[1][ks], bw1, acc1);
        }
        const float bias = b1[n];
        #pragma unroll
        for (int mt = 0; mt < 2; ++mt) {
            f32x4 acc = mt ? acc1 : acc0;
            #pragma unroll
            for (int i = 0; i < 4; ++i) {
                const int r = r0 + mt * 16 + 4 * g + i;
                out[(size_t)r * 256 + n] = acc[i] + bias;
            }
        }
    }
}

// ---------------------------------------------------------------------------
extern "C" void kernel_launch(void* const* d_in, const int* in_sizes, int n_in,
                              void* d_out, int out_size, void* d_ws, size_t ws_size,
                              hipStream_t stream) {
    const float* hidden = (const float*)d_in[0];
    const float* enc    = (const float*)d_in[1];
    const float* sine   = (const float*)d_in[2];
    const float* encpos = (const float*)d_in[3];
    const float* qpos   = (const float*)d_in[4];
    const float* qc_w = (const float*)d_in[5];  const float* qc_b = (const float*)d_in[6];
    const float* qp_w = (const float*)d_in[7];  const float* qp_b = (const float*)d_in[8];
    const float* kc_w = (const float*)d_in[9];  const float* kc_b = (const float*)d_in[10];
    const float* kp_w = (const float*)d_in[11]; const float* kp_b = (const float*)d_in[12];
    const float* v_w  = (const float*)d_in[13]; const float* v_b  = (const float*)d_in[14];
    const float* qs_w = (const float*)d_in[15]; const float* qs_b = (const float*)d_in[16];
    const float* o_w  = (const float*)d_in[17]; const float* o_b  = (const float*)d_in[18];

    float* out = (float*)d_out;
    float* attn_out = out;                          // [B][Q][256]
    float* w_out    = out + (size_t)NB * NQ * 256;  // [B][NH][Q][K]

    char* ws = (char*)d_ws;
    bf16* q_full    = (bf16*)ws;                        //  9,830,400
    bf16* k_full    = (bf16*)(ws + 9830400);            // 67,108,864
    bf16* v_t       = (bf16*)(ws + 76939264);           // 33,554,432
    float* attn_tmp = (float*)(ws + 110493696);         //  9,830,400
    bf16* wbf       = (bf16*)(ws + 120324096);          //    917,504
    float* inv_arr  = (float*)(ws + 121241600);         //    307,200

    wprep_kernel<<<224, 256, 0, stream>>>(qc_w, qp_w, kc_w, kp_w, v_w, qs_w, o_w, wbf);

    qproj_kernel<<<300, 128, 0, stream>>>(hidden, qpos, sine,
        wbf + 0 * 65536, wbf + 1 * 65536, wbf + 5 * 65536,
        qc_b, qp_b, qs_b, q_full);
    kvproj_kernel<<<1024, 256, 0, stream>>>(enc, encpos,
        wbf + 2 * 65536, wbf + 3 * 65536, wbf + 4 * 65536,
        kc_b, kp_b, v_b, k_full, v_t);

    attn1_kernel<<<1280, 256, 0, stream>>>(q_full, k_full, inv_arr);
    attn2_kernel<<<1280, 256, 0, stream>>>(q_full, k_full, v_t, inv_arr, w_out, attn_tmp);

    oproj_kernel<<<150, 256, 0, stream>>>(attn_tmp, wbf + 6 * 65536, o_b, attn_out);
}